// Round 1
// baseline (461.420 us; speedup 1.0000x reference)
//
#include <hip/hip_runtime.h>

// Problem constants
#define DIMX 2048
#define SEQ  2048
#define BATCH 2
#define NH   16
#define NKV  8
#define HD   128
#define MTOK (BATCH*SEQ)   // 4096 tokens
#define NQKV 4096          // 2048 (Q) + 1024 (K) + 1024 (V)

typedef __bf16 bf16x8 __attribute__((ext_vector_type(8)));
typedef float  f32x4  __attribute__((ext_vector_type(4)));
typedef unsigned short u16x8 __attribute__((ext_vector_type(8)));

__device__ __forceinline__ unsigned short f2bf(float f) {
    unsigned u = __builtin_bit_cast(unsigned, f);
    u += 0x7fffu + ((u >> 16) & 1u);            // RNE
    return (unsigned short)(u >> 16);
}
__device__ __forceinline__ float bf2f(unsigned short h) {
    unsigned u = ((unsigned)h) << 16;
    return __builtin_bit_cast(float, u);
}

__device__ __forceinline__ void gload16(const void* g, void* l) {
    __builtin_amdgcn_global_load_lds(
        (const __attribute__((address_space(1))) unsigned int*)g,
        (__attribute__((address_space(3))) unsigned int*)l, 16, 0, 0);
}

// ---------------- fp32 -> bf16 elementwise convert (8 elems/thread) ----------------
__global__ __launch_bounds__(256) void k_convert(const float* __restrict__ in,
                                                 unsigned short* __restrict__ out, int n8) {
    int i = blockIdx.x * 256 + threadIdx.x;
    if (i >= n8) return;
    f32x4 a = ((const f32x4*)in)[(size_t)i*2];
    f32x4 b = ((const f32x4*)in)[(size_t)i*2+1];
    u16x8 o;
    o[0]=f2bf(a[0]); o[1]=f2bf(a[1]); o[2]=f2bf(a[2]); o[3]=f2bf(a[3]);
    o[4]=f2bf(b[0]); o[5]=f2bf(b[1]); o[6]=f2bf(b[2]); o[7]=f2bf(b[3]);
    ((u16x8*)out)[i] = o;
}

// ---------------- fp32 KxN -> bf16 NxK transpose (64x64 tiles via LDS) ----------------
__global__ __launch_bounds__(256) void k_transpose(const float* __restrict__ W,
                                                   unsigned short* __restrict__ Wt,
                                                   int K, int N) {
    __shared__ unsigned short tile[64*65];
    int t = threadIdx.x;
    int n0 = blockIdx.x * 64, k0 = blockIdx.y * 64;
    #pragma unroll
    for (int i = 0; i < 16; ++i) {
        int idx = t + i*256, r = idx >> 6, c = idx & 63;
        tile[r*65+c] = f2bf(W[(size_t)(k0+r)*N + n0 + c]);
    }
    __syncthreads();
    #pragma unroll
    for (int i = 0; i < 16; ++i) {
        int idx = t + i*256, n = idx >> 6, k = idx & 63;
        Wt[(size_t)(n0+n)*K + k0 + k] = tile[k*65+n];
    }
}

// ---------------- bf16 GEMM, m97 structure: A(MxK) row-major, Bt(NxK) row-major ----------------
// 128x128 tile, BK=32, 4 waves (2x2), each wave 64x64 = 4x4 frags of 16x16x32.
template<int OUTF32>
__global__ __launch_bounds__(256) void k_gemm(const unsigned short* __restrict__ A,
                                              const unsigned short* __restrict__ Bt,
                                              void* __restrict__ Cv,
                                              int M, int N, int K) {
    __shared__ unsigned short As[128*32];
    __shared__ unsigned short Bs[128*32];
    int tid = threadIdx.x;
    int wave = tid >> 6, lane = tid & 63;
    int g = lane >> 4, r16 = lane & 15;
    int row0 = blockIdx.y * 128, col0 = blockIdx.x * 128;
    int wr = wave >> 1, wc = wave & 1;
    f32x4 acc[4][4] = {};
    // global_load_lds: chunk c covers LDS bytes [c*1024,(c+1)*1024): row=c*16+lane/4, col=(lane&3)*8
    const unsigned short* ga = A  + (size_t)(row0 + wave*32 + (lane>>2))*K + (lane&3)*8;
    const unsigned short* gb = Bt + (size_t)(col0 + wave*32 + (lane>>2))*K + (lane&3)*8;
    unsigned short* lA = As + wave*1024;
    unsigned short* lB = Bs + wave*1024;
    for (int k0 = 0; k0 < K; k0 += 32) {
        __syncthreads();
        gload16(ga + k0,                 lA);
        gload16(ga + k0 + (size_t)16*K, lA + 512);
        gload16(gb + k0,                 lB);
        gload16(gb + k0 + (size_t)16*K, lB + 512);
        __syncthreads();
        bf16x8 af[4], bfr[4];
        #pragma unroll
        for (int mi = 0; mi < 4; ++mi)
            af[mi] = *(const bf16x8*)&As[(wr*64 + mi*16 + r16)*32 + g*8];
        #pragma unroll
        for (int ni = 0; ni < 4; ++ni)
            bfr[ni] = *(const bf16x8*)&Bs[(wc*64 + ni*16 + r16)*32 + g*8];
        #pragma unroll
        for (int mi = 0; mi < 4; ++mi)
            #pragma unroll
            for (int ni = 0; ni < 4; ++ni)
                acc[mi][ni] = __builtin_amdgcn_mfma_f32_16x16x32_bf16(af[mi], bfr[ni], acc[mi][ni], 0, 0, 0);
    }
    #pragma unroll
    for (int mi = 0; mi < 4; ++mi)
        #pragma unroll
        for (int ni = 0; ni < 4; ++ni)
            #pragma unroll
            for (int rr = 0; rr < 4; ++rr) {
                int row = row0 + wr*64 + mi*16 + g*4 + rr;
                int col = col0 + wc*64 + ni*16 + r16;
                float v = acc[mi][ni][rr];
                if (OUTF32) ((float*)Cv)[(size_t)row*N + col] = v;
                else ((unsigned short*)Cv)[(size_t)row*N + col] = f2bf(v);
            }
}

// ---------------- RoPE in place on Q and K columns of the QKV buffer ----------------
__global__ __launch_bounds__(256) void k_rope(unsigned short* __restrict__ qkv) {
    int tid = blockIdx.x * 256 + threadIdx.x;   // MTOK*(NH+NKV)*64 threads
    int i    = tid & 63;                        // rotation pair index
    int rest = tid >> 6;
    int head = rest % (NH + NKV);
    int tok  = rest / (NH + NKV);
    int pos  = tok & (SEQ - 1);
    int col  = (head < NH) ? head*HD : DIMX + (head-NH)*HD;
    size_t base = (size_t)tok * NQKV + col;
    float x1 = bf2f(qkv[base + i]);
    float x2 = bf2f(qkv[base + i + 64]);
    float inv = exp2f(-0.20762050593046014f * (float)i);   // 10000^(-i/64)
    float ang = (float)pos * inv;
    float s, c;
    sincosf(ang, &s, &c);
    qkv[base + i]      = f2bf(x1*c - x2*s);
    qkv[base + i + 64] = f2bf(x2*c + x1*s);
}

// ---------------- causal GQA flash attention ----------------
// grid: (SEQ/64, BATCH*NH). 4 waves/block, wave owns 16 q-rows; KVBLK=64.
__global__ __launch_bounds__(256) void k_attn(const unsigned short* __restrict__ qkv,
                                              unsigned short* __restrict__ attn_out) {
    __shared__ unsigned short Ks[64*136];        // [kv][d], stride 136 (2-way reads)
    __shared__ unsigned short Vt[128*72];        // [d][kv] swizzled, stride 72
    __shared__ unsigned short Pl[4][16*72];      // per-wave P tile [q][kv]
    int qt = blockIdx.x, bh = blockIdx.y;
    int b = bh >> 4, h = bh & 15;
    int kvh = h >> 1;
    int tid = threadIdx.x, wave = tid >> 6, lane = tid & 63;
    int g = lane >> 4, r16 = lane & 15;
    int q0w = qt*64 + wave*16;
    const size_t rowbase = (size_t)b * SEQ * NQKV;
    const int qcol = h * HD, kcol = DIMX + kvh*HD, vcol = DIMX + NKV*HD + kvh*HD;

    bf16x8 qf[4];
    #pragma unroll
    for (int dc = 0; dc < 4; ++dc)
        qf[dc] = *(const bf16x8*)(qkv + rowbase + (size_t)(q0w + r16)*NQKV + qcol + dc*32 + g*8);

    f32x4 acc[8] = {};
    float mrow[4] = {-1e30f,-1e30f,-1e30f,-1e30f};
    float lrow[4] = {0.f,0.f,0.f,0.f};
    const float SC = 0.08838834764831845f * 1.4426950408889634f;  // (1/sqrt(128))*log2(e)

    int ntiles = qt + 1;
    for (int it = 0; it < ntiles; ++it) {
        int kv0 = it * 64;
        __syncthreads();
        {   // stage K [64][128] -> Ks stride 136
            int rr = tid >> 4, cc = (tid & 15) * 8;
            #pragma unroll
            for (int p = 0; p < 4; ++p) {
                int row = rr + p*16;
                u16x8 kv8 = *(const u16x8*)(qkv + rowbase + (size_t)(kv0+row)*NQKV + kcol + cc);
                *(u16x8*)&Ks[row*136 + cc] = kv8;
            }
            // stage V transposed+swizzled: elem (kv,d) at d*72 + ((kv>>3 ^ d>>3)&7)*8 + (kv&7)
            int vr = (tid >> 4) * 2, vc = (tid & 15) * 8;
            #pragma unroll
            for (int p = 0; p < 2; ++p) {
                int row = vr + p*32;
                u16x8 v0 = *(const u16x8*)(qkv + rowbase + (size_t)(kv0+row)*NQKV   + vcol + vc);
                u16x8 v1 = *(const u16x8*)(qkv + rowbase + (size_t)(kv0+row+1)*NQKV + vcol + vc);
                #pragma unroll
                for (int j = 0; j < 8; ++j) {
                    int d = vc + j;
                    unsigned val = (unsigned)v0[j] | ((unsigned)v1[j] << 16);
                    int off = d*72 + ((((row>>3) ^ (d>>3)) & 7) << 3) + (row & 7);
                    *(unsigned*)&Vt[off] = val;
                }
            }
        }
        __syncthreads();
        // S = Q K^T  (4 kv-subtiles of 16)
        f32x4 s[4] = {};
        #pragma unroll
        for (int nt = 0; nt < 4; ++nt)
            #pragma unroll
            for (int dc = 0; dc < 4; ++dc) {
                bf16x8 kf = *(const bf16x8*)&Ks[(nt*16 + r16)*136 + dc*32 + g*8];
                s[nt] = __builtin_amdgcn_mfma_f32_16x16x32_bf16(qf[dc], kf, s[nt], 0, 0, 0);
            }
        // scale (into log2 units) + causal mask + row max
        float mnew[4] = {-1e30f,-1e30f,-1e30f,-1e30f};
        #pragma unroll
        for (int nt = 0; nt < 4; ++nt)
            #pragma unroll
            for (int rr = 0; rr < 4; ++rr) {
                int qrow = q0w + g*4 + rr;
                int kv = kv0 + nt*16 + r16;
                float v = (kv <= qrow) ? s[nt][rr]*SC : -1e30f;
                s[nt][rr] = v;
                mnew[rr] = fmaxf(mnew[rr], v);
            }
        #pragma unroll
        for (int msk = 1; msk <= 8; msk <<= 1)
            #pragma unroll
            for (int rr = 0; rr < 4; ++rr)
                mnew[rr] = fmaxf(mnew[rr], __shfl_xor(mnew[rr], msk, 64));
        float corr[4];
        #pragma unroll
        for (int rr = 0; rr < 4; ++rr) {
            float mo = mrow[rr];
            float mn = fmaxf(mo, mnew[rr]);
            mrow[rr] = mn;
            corr[rr] = exp2f(mo - mn);
        }
        // P = exp2(s-m), row sums, P tile -> LDS (bf16)
        float rs[4] = {0.f,0.f,0.f,0.f};
        #pragma unroll
        for (int nt = 0; nt < 4; ++nt)
            #pragma unroll
            for (int rr = 0; rr < 4; ++rr) {
                float p = exp2f(s[nt][rr] - mrow[rr]);
                rs[rr] += p;
                Pl[wave][(g*4+rr)*72 + nt*16 + r16] = f2bf(p);
            }
        #pragma unroll
        for (int msk = 1; msk <= 8; msk <<= 1)
            #pragma unroll
            for (int rr = 0; rr < 4; ++rr)
                rs[rr] += __shfl_xor(rs[rr], msk, 64);
        #pragma unroll
        for (int rr = 0; rr < 4; ++rr) lrow[rr] = lrow[rr]*corr[rr] + rs[rr];
        // rescale O
        #pragma unroll
        for (int dt = 0; dt < 8; ++dt)
            #pragma unroll
            for (int rr = 0; rr < 4; ++rr)
                acc[dt][rr] *= corr[rr];
        // PV
        bf16x8 pf[2];
        #pragma unroll
        for (int c = 0; c < 2; ++c)
            pf[c] = *(const bf16x8*)&Pl[wave][r16*72 + c*32 + g*8];
        #pragma unroll
        for (int dt = 0; dt < 8; ++dt)
            #pragma unroll
            for (int c = 0; c < 2; ++c) {
                int d = dt*16 + r16;
                int off = d*72 + ((((c*4+g) ^ ((d>>3)&7)) & 7) << 3);
                bf16x8 vf = *(const bf16x8*)&Vt[off];
                acc[dt] = __builtin_amdgcn_mfma_f32_16x16x32_bf16(pf[c], vf, acc[dt], 0, 0, 0);
            }
    }
    // epilogue: normalize, write bf16 attn_out (token-major, col = h*128+d)
    #pragma unroll
    for (int dt = 0; dt < 8; ++dt)
        #pragma unroll
        for (int rr = 0; rr < 4; ++rr) {
            int qrow = q0w + g*4 + rr;
            int col = h*HD + dt*16 + r16;
            float o = acc[dt][rr] / lrow[rr];
            attn_out[(size_t)(b*SEQ + qrow)*DIMX + col] = f2bf(o);
        }
}

extern "C" void kernel_launch(void* const* d_in, const int* in_sizes, int n_in,
                              void* d_out, int out_size, void* d_ws, size_t ws_size,
                              hipStream_t stream) {
    const float* x  = (const float*)d_in[0];
    const float* Wq = (const float*)d_in[1];
    const float* Wk = (const float*)d_in[2];
    const float* Wv = (const float*)d_in[3];
    const float* Wo = (const float*)d_in[4];

    // ws layout (all bf16/ushort), total ~92.3 MB
    unsigned short* xb   = (unsigned short*)d_ws;                 // 4096x2048
    unsigned short* Wtq  = xb  + (size_t)MTOK*DIMX;               // 4096x2048 (QKV weights, NxK)
    unsigned short* Wto  = Wtq + (size_t)NQKV*DIMX;               // 2048x2048 (Wo^T)
    unsigned short* qkv  = Wto + (size_t)DIMX*DIMX;               // 4096x4096
    unsigned short* aout = qkv + (size_t)MTOK*NQKV;               // 4096x2048

    k_convert<<<(MTOK*DIMX/8 + 255)/256, 256, 0, stream>>>(x, xb, MTOK*DIMX/8);

    dim3 tg32(DIMX/64, DIMX/64);
    dim3 tg16(1024/64, DIMX/64);
    k_transpose<<<tg32, 256, 0, stream>>>(Wq, Wtq,                         DIMX, DIMX);
    k_transpose<<<tg16, 256, 0, stream>>>(Wk, Wtq + (size_t)2048*DIMX,     DIMX, 1024);
    k_transpose<<<tg16, 256, 0, stream>>>(Wv, Wtq + (size_t)3072*DIMX,     DIMX, 1024);
    k_transpose<<<tg32, 256, 0, stream>>>(Wo, Wto,                         DIMX, DIMX);

    dim3 g1(NQKV/128, MTOK/128);
    k_gemm<0><<<g1, 256, 0, stream>>>(xb, Wtq, qkv, MTOK, NQKV, DIMX);

    k_rope<<<(MTOK*(NH+NKV)*64)/256, 256, 0, stream>>>(qkv);

    dim3 ga(SEQ/64, BATCH*NH);
    k_attn<<<ga, 256, 0, stream>>>(qkv, aout);

    dim3 g2(DIMX/128, MTOK/128);
    k_gemm<1><<<g2, 256, 0, stream>>>(aout, Wto, (float*)d_out, MTOK, DIMX, DIMX);
}

// Round 2
// 339.751 us; speedup vs baseline: 1.3581x; 1.3581x over previous
//
#include <hip/hip_runtime.h>

// Problem constants
#define DIMX 2048
#define SEQ  2048
#define BATCH 2
#define NH   16
#define NKV  8
#define HD   128
#define MTOK (BATCH*SEQ)   // 4096 tokens
#define NQKV 4096          // GEMM1 output cols: 2048 Q + 1024 K + 1024 V
#define QKLD 3072          // qkv buffer stride (Q+K only; V goes to Vt)

typedef __bf16 bf16x8 __attribute__((ext_vector_type(8)));
typedef float  f32x4  __attribute__((ext_vector_type(4)));
typedef unsigned short u16x8 __attribute__((ext_vector_type(8)));
typedef unsigned short u16x4 __attribute__((ext_vector_type(4)));

__device__ __forceinline__ unsigned short f2bf(float f) {
    unsigned u = __builtin_bit_cast(unsigned, f);
    u += 0x7fffu + ((u >> 16) & 1u);            // RNE
    return (unsigned short)(u >> 16);
}
__device__ __forceinline__ float bf2f(unsigned short h) {
    unsigned u = ((unsigned)h) << 16;
    return __builtin_bit_cast(float, u);
}

__device__ __forceinline__ void gload16(const void* g, void* l) {
    __builtin_amdgcn_global_load_lds(
        (const __attribute__((address_space(1))) unsigned int*)g,
        (__attribute__((address_space(3))) unsigned int*)l, 16, 0, 0);
}

// ---------------- fp32 -> bf16 elementwise convert (8 elems/thread) ----------------
__global__ __launch_bounds__(256) void k_convert(const float* __restrict__ in,
                                                 unsigned short* __restrict__ out, int n8) {
    int i = blockIdx.x * 256 + threadIdx.x;
    if (i >= n8) return;
    f32x4 a = ((const f32x4*)in)[(size_t)i*2];
    f32x4 b = ((const f32x4*)in)[(size_t)i*2+1];
    u16x8 o;
    o[0]=f2bf(a[0]); o[1]=f2bf(a[1]); o[2]=f2bf(a[2]); o[3]=f2bf(a[3]);
    o[4]=f2bf(b[0]); o[5]=f2bf(b[1]); o[6]=f2bf(b[2]); o[7]=f2bf(b[3]);
    ((u16x8*)out)[i] = o;
}

// ---------------- fp32 KxN -> bf16 NxK transpose (64x64 tiles via LDS) ----------------
__global__ __launch_bounds__(256) void k_transpose(const float* __restrict__ W,
                                                   unsigned short* __restrict__ Wt,
                                                   int K, int N) {
    __shared__ unsigned short tile[64*65];
    int t = threadIdx.x;
    int n0 = blockIdx.x * 64, k0 = blockIdx.y * 64;
    #pragma unroll
    for (int i = 0; i < 16; ++i) {
        int idx = t + i*256, r = idx >> 6, c = idx & 63;
        tile[r*65+c] = f2bf(W[(size_t)(k0+r)*N + n0 + c]);
    }
    __syncthreads();
    #pragma unroll
    for (int i = 0; i < 16; ++i) {
        int idx = t + i*256, n = idx >> 6, k = idx & 63;
        Wt[(size_t)(n0+n)*K + k0 + k] = tile[k*65+n];
    }
}

// ---------------- bf16 GEMM, m97 structure ----------------
// MODE 0: bf16 C with ldc; blocks with col0>=3072 write V transposed to Vt.
// MODE 1: fp32 C with ldc.
template<int MODE>
__global__ __launch_bounds__(256) void k_gemm(const unsigned short* __restrict__ A,
                                              const unsigned short* __restrict__ Bt,
                                              void* __restrict__ Cv,
                                              unsigned short* __restrict__ Vt,
                                              int M, int N, int K, int ldc) {
    __shared__ unsigned short As[128*32];
    __shared__ unsigned short Bs[128*32];
    int tid = threadIdx.x;
    int wave = tid >> 6, lane = tid & 63;
    int g = lane >> 4, r16 = lane & 15;
    int row0 = blockIdx.y * 128, col0 = blockIdx.x * 128;
    int wr = wave >> 1, wc = wave & 1;
    f32x4 acc[4][4] = {};
    const unsigned short* ga = A  + (size_t)(row0 + wave*32 + (lane>>2))*K + (lane&3)*8;
    const unsigned short* gb = Bt + (size_t)(col0 + wave*32 + (lane>>2))*K + (lane&3)*8;
    unsigned short* lA = As + wave*1024;
    unsigned short* lB = Bs + wave*1024;
    for (int k0 = 0; k0 < K; k0 += 32) {
        __syncthreads();
        gload16(ga + k0,                 lA);
        gload16(ga + k0 + (size_t)16*K, lA + 512);
        gload16(gb + k0,                 lB);
        gload16(gb + k0 + (size_t)16*K, lB + 512);
        __syncthreads();
        bf16x8 af[4], bfr[4];
        #pragma unroll
        for (int mi = 0; mi < 4; ++mi)
            af[mi] = *(const bf16x8*)&As[(wr*64 + mi*16 + r16)*32 + g*8];
        #pragma unroll
        for (int ni = 0; ni < 4; ++ni)
            bfr[ni] = *(const bf16x8*)&Bs[(wc*64 + ni*16 + r16)*32 + g*8];
        #pragma unroll
        for (int mi = 0; mi < 4; ++mi)
            #pragma unroll
            for (int ni = 0; ni < 4; ++ni)
                acc[mi][ni] = __builtin_amdgcn_mfma_f32_16x16x32_bf16(af[mi], bfr[ni], acc[mi][ni], 0, 0, 0);
    }
    if (MODE == 0 && col0 >= 3072) {
        // V columns: store transposed as Vt[b][kvh][d][s], packed 4 bf16 along s
        #pragma unroll
        for (int mi = 0; mi < 4; ++mi)
            #pragma unroll
            for (int ni = 0; ni < 4; ++ni) {
                int vcol = col0 + wc*64 + ni*16 + r16 - 3072;
                int d = vcol & 127, kh = vcol >> 7;
                int row = row0 + wr*64 + mi*16 + g*4;
                int b = row >> 11, s = row & (SEQ-1);
                u16x4 pk;
                #pragma unroll
                for (int rr = 0; rr < 4; ++rr) pk[rr] = f2bf(acc[mi][ni][rr]);
                *(u16x4*)&Vt[((size_t)(b*NKV + kh)*HD + d)*SEQ + s] = pk;
            }
    } else {
        #pragma unroll
        for (int mi = 0; mi < 4; ++mi)
            #pragma unroll
            for (int ni = 0; ni < 4; ++ni)
                #pragma unroll
                for (int rr = 0; rr < 4; ++rr) {
                    int row = row0 + wr*64 + mi*16 + g*4 + rr;
                    int col = col0 + wc*64 + ni*16 + r16;
                    float v = acc[mi][ni][rr];
                    if (MODE == 1) ((float*)Cv)[(size_t)row*ldc + col] = v;
                    else ((unsigned short*)Cv)[(size_t)row*ldc + col] = f2bf(v);
                }
    }
}

// ---------------- RoPE in place on Q and K columns of the qkv buffer (ld=3072) ----------------
__global__ __launch_bounds__(256) void k_rope(unsigned short* __restrict__ qkv) {
    int tid = blockIdx.x * 256 + threadIdx.x;   // MTOK*(NH+NKV)*64 threads
    int i    = tid & 63;                        // rotation pair index
    int rest = tid >> 6;
    int head = rest % (NH + NKV);
    int tok  = rest / (NH + NKV);
    int pos  = tok & (SEQ - 1);
    size_t base = (size_t)tok * QKLD + head*HD;
    float x1 = bf2f(qkv[base + i]);
    float x2 = bf2f(qkv[base + i + 64]);
    float inv = exp2f(-0.20762050593046014f * (float)i);   // 10000^(-i/64)
    float ang = (float)pos * inv;
    float s, c;
    sincosf(ang, &s, &c);
    qkv[base + i]      = f2bf(x1*c - x2*s);
    qkv[base + i + 64] = f2bf(x2*c + x1*s);
}

// ---------------- causal GQA flash attention, swapped-operand 16x16 design ----------------
// grid: (SEQ/128, BATCH*NH), 512 threads (8 waves), wave owns 16 q-rows. KVBLK=64.
// S^T = mfma(K_frag, Q_frag): lane holds q=lane&15, kv=(lane>>4)*4+reg -> lane-local softmax row.
// O^T = mfma(Vt_frag, P_frag): lane holds q=lane&15, d=dt*16+(lane>>4)*4+reg.
__global__ __launch_bounds__(512) void k_attn(const unsigned short* __restrict__ qkv,
                                              const unsigned short* __restrict__ Vt,
                                              unsigned short* __restrict__ attn_out) {
    __shared__ __align__(16) unsigned short Ks[64*128];   // [kv][d] linear, reads XOR-swizzled
    __shared__ __align__(16) unsigned short Vs[128*64];   // [d][kv] linear, reads XOR-swizzled
    __shared__ __align__(16) unsigned short Pl[8][16*64]; // per-wave P, XOR-swizzled
    int qt = (int)gridDim.x - 1 - blockIdx.x;             // big-work blocks first
    int bh = blockIdx.y;
    int b = bh >> 4, h = bh & 15;
    int kvh = h >> 1;
    int tid = threadIdx.x, wave = tid >> 6, lane = tid & 63;
    int g = lane >> 4, r16 = lane & 15;
    int q0w = qt*128 + wave*16;
    int qrow = q0w + r16;                                  // this lane's q row
    const unsigned short* qbase = qkv + (size_t)(b*SEQ)*QKLD;
    const char* kbase = (const char*)(qbase + (size_t)0*QKLD + DIMX + kvh*HD);  // + row*QKLD*2 bytes
    const char* vbase = (const char*)(Vt + ((size_t)(b*NKV + kvh)*HD)*SEQ);     // + d*SEQ*2 bytes

    // Q fragments: lane holds Q[q=r16][dc*32 + g*8 ..+8]
    bf16x8 qf[4];
    #pragma unroll
    for (int dc = 0; dc < 4; ++dc)
        qf[dc] = *(const bf16x8*)(qbase + (size_t)qrow*QKLD + h*HD + dc*32 + g*8);

    f32x4 acc[8] = {};
    float mrow = -1e30f, lrow = 0.f;
    const float SC = 0.08838834764831845f * 1.4426950408889634f;  // rsqrt(128)*log2(e)
    char* Plw = (char*)&Pl[wave][0];

    int ntiles = 2*qt + 2;
    for (int it = 0; it < ntiles; ++it) {
        int kv0 = it * 64;
        __syncthreads();
        {   // stage K (16KB) + Vt (16KB) via global_load_lds, 2+2 chunks per wave.
            // LDS linear; global source pre-swizzled so XOR-swizzled reads are conflict-free.
            #pragma unroll
            for (int p = 0; p < 2; ++p) {
                unsigned c = wave*2 + p;
                unsigned o = c*1024 + lane*16;
                unsigned ok = o ^ (((o >> 8) & 7) << 5);   // K rows 256B
                gload16(kbase + (size_t)(kv0 + (ok >> 8))*(QKLD*2) + (ok & 255),
                        (char*)Ks + c*1024);
                unsigned ov = o ^ (((o >> 7) & 7) << 4);   // V rows 128B
                gload16(vbase + (size_t)(ov >> 7)*(SEQ*2) + kv0*2 + (ov & 127),
                        (char*)Vs + c*1024);
            }
        }
        __syncthreads();
        if (kv0 > q0w + 15) continue;   // fully masked for this wave (barriers stay uniform)

        // S^T = K . Q^T : s4[nt] covers kv = kv0 + nt*16 + g*4 + reg, q = r16
        f32x4 s4[4] = {};
        #pragma unroll
        for (int nt = 0; nt < 4; ++nt)
            #pragma unroll
            for (int dc = 0; dc < 4; ++dc) {
                unsigned o = (nt*16 + r16)*256 + dc*64 + g*16;
                bf16x8 kf = *(const bf16x8*)((char*)Ks + (o ^ ((r16 & 7) << 5)));
                s4[nt] = __builtin_amdgcn_mfma_f32_16x16x32_bf16(kf, qf[dc], s4[nt], 0, 0, 0);
            }
        // scale + (diagonal-only) causal mask + lane-local row max
        float mt = -1e30f;
        if (kv0 + 63 > q0w) {
            #pragma unroll
            for (int nt = 0; nt < 4; ++nt)
                #pragma unroll
                for (int rr = 0; rr < 4; ++rr) {
                    int kv = kv0 + nt*16 + g*4 + rr;
                    float v = (kv <= qrow) ? s4[nt][rr]*SC : -1e30f;
                    s4[nt][rr] = v; mt = fmaxf(mt, v);
                }
        } else {
            #pragma unroll
            for (int nt = 0; nt < 4; ++nt)
                #pragma unroll
                for (int rr = 0; rr < 4; ++rr) {
                    float v = s4[nt][rr]*SC;
                    s4[nt][rr] = v; mt = fmaxf(mt, v);
                }
        }
        mt = fmaxf(mt, __shfl_xor(mt, 16, 64));
        mt = fmaxf(mt, __shfl_xor(mt, 32, 64));
        float mn = fmaxf(mrow, mt);
        float corr = exp2f(mrow - mn);
        mrow = mn;
        // P = exp2(s-m), packed bf16 pairs; lane-local row sum
        float rs = 0.f;
        unsigned pk[4][2];
        #pragma unroll
        for (int nt = 0; nt < 4; ++nt)
            #pragma unroll
            for (int hh = 0; hh < 2; ++hh) {
                float p0 = exp2f(s4[nt][2*hh]   - mn);
                float p1 = exp2f(s4[nt][2*hh+1] - mn);
                rs += p0 + p1;
                pk[nt][hh] = (unsigned)f2bf(p0) | ((unsigned)f2bf(p1) << 16);
            }
        rs += __shfl_xor(rs, 16, 64);
        rs += __shfl_xor(rs, 32, 64);
        lrow = lrow*corr + rs;
        #pragma unroll
        for (int dt = 0; dt < 8; ++dt)
            #pragma unroll
            for (int rr = 0; rr < 4; ++rr)
                acc[dt][rr] *= corr;
        // P -> per-wave swizzled LDS (8 dword writes), read back as 2 A-frag b128s
        #pragma unroll
        for (int nt = 0; nt < 4; ++nt)
            #pragma unroll
            for (int hh = 0; hh < 2; ++hh) {
                unsigned o = r16*128 + nt*32 + g*8 + hh*4;
                *(unsigned*)(Plw + (o ^ ((r16 & 7) << 4))) = pk[nt][hh];
            }
        bf16x8 pf[2];
        #pragma unroll
        for (int kvc = 0; kvc < 2; ++kvc) {
            unsigned o = r16*128 + kvc*64 + g*16;
            pf[kvc] = *(const bf16x8*)(Plw + (o ^ ((r16 & 7) << 4)));
        }
        // O^T += Vt . P : acc[dt] lane holds d = dt*16 + g*4 + reg, q = r16
        #pragma unroll
        for (int dt = 0; dt < 8; ++dt)
            #pragma unroll
            for (int kvc = 0; kvc < 2; ++kvc) {
                unsigned o = (dt*16 + r16)*128 + kvc*64 + g*16;
                bf16x8 vf = *(const bf16x8*)((char*)Vs + (o ^ ((r16 & 7) << 4)));
                acc[dt] = __builtin_amdgcn_mfma_f32_16x16x32_bf16(vf, pf[kvc], acc[dt], 0, 0, 0);
            }
    }
    // epilogue: normalize, write bf16 (4 consecutive d per lane -> 8B stores)
    float inv = 1.0f / lrow;
    #pragma unroll
    for (int dt = 0; dt < 8; ++dt) {
        u16x4 o4;
        #pragma unroll
        for (int rr = 0; rr < 4; ++rr) o4[rr] = f2bf(acc[dt][rr] * inv);
        *(u16x4*)&attn_out[(size_t)(b*SEQ + qrow)*DIMX + h*HD + dt*16 + g*4] = o4;
    }
}

extern "C" void kernel_launch(void* const* d_in, const int* in_sizes, int n_in,
                              void* d_out, int out_size, void* d_ws, size_t ws_size,
                              hipStream_t stream) {
    const float* x  = (const float*)d_in[0];
    const float* Wq = (const float*)d_in[1];
    const float* Wk = (const float*)d_in[2];
    const float* Wv = (const float*)d_in[3];
    const float* Wo = (const float*)d_in[4];

    // ws layout (all u16), total 92.3 MB
    unsigned short* xb   = (unsigned short*)d_ws;                 // 4096x2048
    unsigned short* Wtq  = xb  + (size_t)MTOK*DIMX;               // 4096x2048 (QKV weights, NxK)
    unsigned short* Wto  = Wtq + (size_t)NQKV*DIMX;               // 2048x2048 (Wo^T)
    unsigned short* qkv  = Wto + (size_t)DIMX*DIMX;               // 4096x3072 (Q|K, ld 3072)
    unsigned short* aout = qkv + (size_t)MTOK*QKLD;               // 4096x2048
    unsigned short* Vt   = aout + (size_t)MTOK*DIMX;              // [2][8][128][2048]

    k_convert<<<(MTOK*DIMX/8 + 255)/256, 256, 0, stream>>>(x, xb, MTOK*DIMX/8);

    dim3 tg32(DIMX/64, DIMX/64);
    dim3 tg16(1024/64, DIMX/64);
    k_transpose<<<tg32, 256, 0, stream>>>(Wq, Wtq,                         DIMX, DIMX);
    k_transpose<<<tg16, 256, 0, stream>>>(Wk, Wtq + (size_t)2048*DIMX,     DIMX, 1024);
    k_transpose<<<tg16, 256, 0, stream>>>(Wv, Wtq + (size_t)3072*DIMX,     DIMX, 1024);
    k_transpose<<<tg32, 256, 0, stream>>>(Wo, Wto,                         DIMX, DIMX);

    dim3 g1(NQKV/128, MTOK/128);
    k_gemm<0><<<g1, 256, 0, stream>>>(xb, Wtq, qkv, Vt, MTOK, NQKV, DIMX, QKLD);

    k_rope<<<(MTOK*(NH+NKV)*64)/256, 256, 0, stream>>>(qkv);

    dim3 ga(SEQ/128, BATCH*NH);
    k_attn<<<ga, 512, 0, stream>>>(qkv, Vt, aout);

    dim3 g2(DIMX/128, MTOK/128);
    k_gemm<1><<<g2, 256, 0, stream>>>(aout, Wto, (float*)d_out, nullptr, MTOK, DIMX, DIMX, DIMX);
}